// Round 9
// baseline (99.589 us; speedup 1.0000x reference)
//
#include <hip/hip_runtime.h>
#include <math.h>

#define HID 128
#define TPB 1024  // 16 waves; 1 block/CU, LDS 103.5KB
#define NW  16    // waves per block
#define GRIDB 256 // 1 block per CU; 256*16 waves * 32 samples = 131072 = B (single pass)

typedef __bf16 bf16;
typedef bf16 bf16x8 __attribute__((ext_vector_type(8)));
typedef bf16 bf16x4 __attribute__((ext_vector_type(4)));
typedef float floatx4 __attribute__((ext_vector_type(4)));

// rcp-based tanh; packed f32 for everything but the trans ops.
__device__ __forceinline__ floatx4 tanh4(floatx4 z) {
    floatx4 t = z * 2.885390081777927f;                  // exp(2x) via exp2
    floatx4 e = { __builtin_amdgcn_exp2f(t[0]), __builtin_amdgcn_exp2f(t[1]),
                  __builtin_amdgcn_exp2f(t[2]), __builtin_amdgcn_exp2f(t[3]) };
    e = e + 1.0f;
    floatx4 r = { __builtin_amdgcn_rcpf(e[0]), __builtin_amdgcn_rcpf(e[1]),
                  __builtin_amdgcn_rcpf(e[2]), __builtin_amdgcn_rcpf(e[3]) };
    return 1.0f - 2.0f * r;
}

// DUAL-TILE wave-autonomous formulation. r8 post-mortem: kernel is LDS-issue
// bound on weight A-line re-reads (~64 full-width ds_read_b128 per 16-sample
// tile => ~16-20us floor). THIS round: each wave owns 32 samples (2 tiles);
// every weight A-line read feeds TWO MFMAs => weight LDS traffic per sample
// halves. Grid covers B in ONE pass (no loop re-streaming).
// Transforms run LINE-BY-LINE through two 1KB wave-private buffers (lb0/lb1):
// write line L (both tiles) -> read gB/sv[L] -> reuse buffers for L+1.
// DS ops are in-order per wave => no barrier; scratch stays 2KB/wave.
// GEMM3 fused into the L-loop: S-line L == K-slice m=L of GEMM3 (k=32L+..).
//
// MFMA 16x16x32 layouts:
//   A-frag: lane holds A[m=lane&15][k=(lane>>4)*8+idx]
//   B-frag: lane holds B[k=(lane>>4)*8+idx][n=lane&15]
//   C/D:    lane/reg holds D[row=(lane>>4)*4+reg][col=lane&15]
// Sample ALWAYS = lane&15 (per tile). P1 makes H1^T B-frags in regs (breg).
// GEMM1t: Z2^T = W2^T @ H1^T (A=sW2A lines, B=breg)
// GEMM2t: S^T  = W2 @ G2^T   (A=sW2R lines, B=gB from line transform)
// GEMM3t: dV^T = W1 @ G1^T   (A=sW1A lines, B=(1-breg^2)*transform(S))
//
// C->B transform (HW-verified r7/r8): C-tile jt, lane(lq,lrow), reg r holds
// k_global=16jt+4lq+r of sample lrow. Line L=jt>>1, b=jt&1:
//   k_local = 16b + 8(lq>>1)+4(lq&1)+r ; elem = lrow*32 + blk*8 + 4(lq&1)+r,
//   blk = (2b+(lq>>1)) ^ (lrow&3)  [XOR swizzle, write AND read].
// Read: lane(lq,lrow) b128-reads elems lrow*32 + (lq^(lrow&3))*8.
// REGISTER BUDGET: breg0/1(32)+gB0/1(32)+rolling accs(8)+dv(8)+temps ~= 106.

__global__ __launch_bounds__(TPB, 1)
void lnn_kernel(const float* __restrict__ X,
                const float* __restrict__ W1,
                const float* __restrict__ b1,
                const float* __restrict__ b2,
                const float* __restrict__ W3,
                const float* __restrict__ W2,
                float* __restrict__ out,
                int B, int nchunk)
{
    // 32KB: W2^T A-frags [(jt*4+kt)*64+lane]*8 : lane(q,lr) = W2[32kt+8q+idx][16jt+lr]
    __shared__ __align__(16) bf16 sW2A[16384];
    // 32KB: W2 row A-frags [(it*4+jt2)*64+lane]*8 : lane(q,lr) = W2[16it+lr][32jt2+8q+idx]
    __shared__ __align__(16) bf16 sW2R[16384];
    // 32KB: per-wave 2 line buffers (tile0 / tile1), 1KB each
    __shared__ __align__(16) bf16 sXf[NW][1024];
    // 4KB: W1 A-frag lines for GEMM3 (rows>=4 zero)
    __shared__ __align__(16) bf16 sW1A[4][512];
    __shared__ __align__(16) float sW1r[4][HID]; // W1 row-major (for P1)
    __shared__ __align__(16) float sB1[HID], sB2[HID], sW3[HID];

    const int tid  = threadIdx.x;
    const int w    = tid >> 6;
    const int lane = tid & 63;
    const int lrow = lane & 15;
    const int lq   = lane >> 4;
    const int swz  = lrow & 3;

    // ---------------- one-time staging ----------------
    if (tid < 512) { int r = tid >> 7, j = tid & (HID - 1); sW1r[r][j] = W1[r * HID + j]; }
    if (tid < HID) sB1[tid] = b1[tid];
    else if (tid < 2 * HID) sB2[tid - HID] = b2[tid - HID];
    else if (tid < 3 * HID) sW3[tid - 2 * HID] = W3[tid - 2 * HID];

    #pragma unroll
    for (int tt = 0; tt < 2; ++tt) {
        int e = tid + tt * TPB;       // 0..2047 frag-line slots
        int t = e >> 6, l = e & 63;
        int a = t >> 2, bidx = t & 3; // (jt,kt) for sW2A ; (it,jt2) for sW2R
        int lr = l & 15, q = l >> 4;
        bf16x8 f;
        #pragma unroll
        for (int idx = 0; idx < 8; ++idx)
            f[idx] = (bf16)W2[(32*bidx + 8*q + idx) * HID + 16*a + lr];
        *reinterpret_cast<bf16x8*>(&sW2A[e * 8]) = f;
        const float4* rp = reinterpret_cast<const float4*>(&W2[(16*a + lr) * HID + 32*bidx + 8*q]);
        float4 r0 = rp[0], r1 = rp[1];
        bf16x8 g;
        g[0]=(bf16)r0.x; g[1]=(bf16)r0.y; g[2]=(bf16)r0.z; g[3]=(bf16)r0.w;
        g[4]=(bf16)r1.x; g[5]=(bf16)r1.y; g[6]=(bf16)r1.z; g[7]=(bf16)r1.w;
        *reinterpret_cast<bf16x8*>(&sW2R[e * 8]) = g;
    }
    if (tid < 256) { // W1 A-frag lines: A[m=lr][k=32m+8q+idx], rows>=4 zero
        int m = tid >> 6, l = tid & 63;
        int lr = l & 15, q = l >> 4;
        bf16x8 f = {};
        if (lr < 4) {
            #pragma unroll
            for (int idx = 0; idx < 8; ++idx)
                f[idx] = (bf16)W1[lr * HID + 32*m + 8*q + idx];
        }
        *reinterpret_cast<bf16x8*>(&sW1A[m][l * 8]) = f;
    }
    __syncthreads(); // ONLY barrier in the kernel

    bf16* const lb0 = &sXf[w][0];   // tile0 line buffer (512 bf16)
    bf16* const lb1 = &sXf[w][512]; // tile1 line buffer

    const int dualStride = GRIDB * NW;
    const int d0 = (int)blockIdx.x * NW + w;
    const floatx4 fz = floatx4{0.f,0.f,0.f,0.f};

    #pragma unroll 1
    for (int c = 0; c < nchunk; ++c) {
        const int dt = d0 + c * dualStride;
        const int S0 = dt * 32;
        if (S0 >= B) break;                     // per-wave divergence OK: no barriers

        int ga = S0 + lrow;      ga = ga < B ? ga : (B - 1);
        int gb = S0 + 16 + lrow; gb = gb < B ? gb : (B - 1);
        float4 x0 = reinterpret_cast<const float4*>(X)[ga];
        float4 x1 = reinterpret_cast<const float4*>(X)[gb];
        float s1a, c1a, s2a, c2a, s1b, c1b, s2b, c2b;
        __sincosf(x0.x, &s1a, &c1a);
        __sincosf(x0.y, &s2a, &c2a);
        __sincosf(x1.x, &s1b, &c1b);
        __sincosf(x1.y, &s2b, &c2b);

        // ---- P1 dual: weight loads shared; breg0/1[kt] = h1[32kt+8lq+idx][sample] ----
        bf16x8 breg0[4], breg1[4];
        #pragma unroll
        for (int kt = 0; kt < 4; ++kt) {
            int jb = 32 * kt + 8 * lq;
            floatx4 w0a = *reinterpret_cast<const floatx4*>(&sW1r[0][jb]);
            floatx4 w0b = *reinterpret_cast<const floatx4*>(&sW1r[0][jb+4]);
            floatx4 w1a = *reinterpret_cast<const floatx4*>(&sW1r[1][jb]);
            floatx4 w1b = *reinterpret_cast<const floatx4*>(&sW1r[1][jb+4]);
            floatx4 w2a = *reinterpret_cast<const floatx4*>(&sW1r[2][jb]);
            floatx4 w2b = *reinterpret_cast<const floatx4*>(&sW1r[2][jb+4]);
            floatx4 w3a = *reinterpret_cast<const floatx4*>(&sW1r[3][jb]);
            floatx4 w3b = *reinterpret_cast<const floatx4*>(&sW1r[3][jb+4]);
            floatx4 bba = *reinterpret_cast<const floatx4*>(&sB1[jb]);
            floatx4 bbb = *reinterpret_cast<const floatx4*>(&sB1[jb+4]);
            floatx4 za = bba + s1a*w0a + c1a*w1a + s2a*w2a + c2a*w3a;
            floatx4 zb = bbb + s1a*w0b + c1a*w1b + s2a*w2b + c2a*w3b;
            floatx4 ha = tanh4(za), hb = tanh4(zb);
            bf16x8 hf;
            hf[0]=(bf16)ha[0]; hf[1]=(bf16)ha[1]; hf[2]=(bf16)ha[2]; hf[3]=(bf16)ha[3];
            hf[4]=(bf16)hb[0]; hf[5]=(bf16)hb[1]; hf[6]=(bf16)hb[2]; hf[7]=(bf16)hb[3];
            breg0[kt] = hf;
            za = bba + s1b*w0a + c1b*w1a + s2b*w2a + c2b*w3a;
            zb = bbb + s1b*w0b + c1b*w1b + s2b*w2b + c2b*w3b;
            ha = tanh4(za); hb = tanh4(zb);
            hf[0]=(bf16)ha[0]; hf[1]=(bf16)ha[1]; hf[2]=(bf16)ha[2]; hf[3]=(bf16)ha[3];
            hf[4]=(bf16)hb[0]; hf[5]=(bf16)hb[1]; hf[6]=(bf16)hb[2]; hf[7]=(bf16)hb[3];
            breg1[kt] = hf;
        }

        // ---- GEMM1t + Phase3 + gB, line-by-line (A-lines shared across tiles) ----
        bf16x8 gB0[4], gB1[4];
        #pragma unroll
        for (int L = 0; L < 4; ++L) {
            #pragma unroll
            for (int b = 0; b < 2; ++b) {
                int jt = 2*L + b;
                bf16x8 A = *reinterpret_cast<const bf16x8*>(&sW2A[((jt*4 + 0)*64 + lane)*8]);
                floatx4 a0 = __builtin_amdgcn_mfma_f32_16x16x32_bf16(A, breg0[0], fz, 0,0,0);
                floatx4 a1 = __builtin_amdgcn_mfma_f32_16x16x32_bf16(A, breg1[0], fz, 0,0,0);
                #pragma unroll
                for (int kt = 1; kt < 4; ++kt) {
                    A = *reinterpret_cast<const bf16x8*>(&sW2A[((jt*4 + kt)*64 + lane)*8]);
                    a0 = __builtin_amdgcn_mfma_f32_16x16x32_bf16(A, breg0[kt], a0, 0,0,0);
                    a1 = __builtin_amdgcn_mfma_f32_16x16x32_bf16(A, breg1[kt], a1, 0,0,0);
                }
                int jb = 16*jt + 4*lq;
                floatx4 b2v = *reinterpret_cast<const floatx4*>(&sB2[jb]);
                floatx4 w3v = *reinterpret_cast<const floatx4*>(&sW3[jb]);
                int blk = (2*b + (lq>>1)) ^ swz;
                int eoff = lrow*32 + blk*8 + 4*(lq&1);
                floatx4 h = tanh4(a0 + b2v);
                floatx4 gv = (1.0f - h*h) * w3v;
                bf16x4 g;
                g[0]=(bf16)gv[0]; g[1]=(bf16)gv[1]; g[2]=(bf16)gv[2]; g[3]=(bf16)gv[3];
                *reinterpret_cast<bf16x4*>(&lb0[eoff]) = g;
                h = tanh4(a1 + b2v);
                gv = (1.0f - h*h) * w3v;
                g[0]=(bf16)gv[0]; g[1]=(bf16)gv[1]; g[2]=(bf16)gv[2]; g[3]=(bf16)gv[3];
                *reinterpret_cast<bf16x4*>(&lb1[eoff]) = g;
            }
            // line L complete for both tiles; in-order DS: reads after writes
            gB0[L] = *reinterpret_cast<const bf16x8*>(&lb0[lrow*32 + (lq ^ swz)*8]);
            gB1[L] = *reinterpret_cast<const bf16x8*>(&lb1[lrow*32 + (lq ^ swz)*8]);
        }

        // ---- GEMM2t + Phase5 + GEMM3t fused, line-by-line ----
        floatx4 dv0 = fz, dv1 = fz;
        #pragma unroll
        for (int L = 0; L < 4; ++L) {
            #pragma unroll
            for (int b = 0; b < 2; ++b) {
                int it = 2*L + b;
                bf16x8 A = *reinterpret_cast<const bf16x8*>(&sW2R[((it*4 + 0)*64 + lane)*8]);
                floatx4 a0 = __builtin_amdgcn_mfma_f32_16x16x32_bf16(A, gB0[0], fz, 0,0,0);
                floatx4 a1 = __builtin_amdgcn_mfma_f32_16x16x32_bf16(A, gB1[0], fz, 0,0,0);
                #pragma unroll
                for (int jt2 = 1; jt2 < 4; ++jt2) {
                    A = *reinterpret_cast<const bf16x8*>(&sW2R[((it*4 + jt2)*64 + lane)*8]);
                    a0 = __builtin_amdgcn_mfma_f32_16x16x32_bf16(A, gB0[jt2], a0, 0,0,0);
                    a1 = __builtin_amdgcn_mfma_f32_16x16x32_bf16(A, gB1[jt2], a1, 0,0,0);
                }
                int blk = (2*b + (lq>>1)) ^ swz;
                int eoff = lrow*32 + blk*8 + 4*(lq&1);
                bf16x4 g;
                g[0]=(bf16)a0[0]; g[1]=(bf16)a0[1]; g[2]=(bf16)a0[2]; g[3]=(bf16)a0[3];
                *reinterpret_cast<bf16x4*>(&lb0[eoff]) = g;
                g[0]=(bf16)a1[0]; g[1]=(bf16)a1[1]; g[2]=(bf16)a1[2]; g[3]=(bf16)a1[3];
                *reinterpret_cast<bf16x4*>(&lb1[eoff]) = g;
            }
            // S-line L ready; K-slice m=L of GEMM3: G1 = (1-h1^2)*S from breg[L]
            bf16x8 sv0 = *reinterpret_cast<const bf16x8*>(&lb0[lrow*32 + (lq ^ swz)*8]);
            bf16x8 sv1 = *reinterpret_cast<const bf16x8*>(&lb1[lrow*32 + (lq ^ swz)*8]);
            bf16x8 A3 = *reinterpret_cast<const bf16x8*>(&sW1A[L][lane*8]);
            bf16x8 g10, g11;
            #pragma unroll
            for (int idx = 0; idx < 8; ++idx) {
                float h0 = (float)breg0[L][idx], s0v = (float)sv0[idx];
                float h1 = (float)breg1[L][idx], s1v = (float)sv1[idx];
                g10[idx] = (bf16)(s0v - s0v*h0*h0);
                g11[idx] = (bf16)(s1v - s1v*h1*h1);
            }
            dv0 = __builtin_amdgcn_mfma_f32_16x16x32_bf16(A3, g10, dv0, 0,0,0);
            dv1 = __builtin_amdgcn_mfma_f32_16x16x32_bf16(A3, g11, dv1, 0,0,0);
        }

        // ---- Epilogues: lanes 0..15 hold dv rows 0..3 for their sample ----
        if (lane < 16 && S0 + lane < B) {
            float dV0 = dv0[0], dV1 = dv0[1], dV2 = dv0[2], dV3 = dv0[3];
            float cosD = c1a * c2a + s1a * s2a;
            float sinD = s1a * c2a - c1a * s2a;
            float dVt1 = dV0 * c1a - dV1 * s1a;
            float dVt2 = dV2 * c2a - dV3 * s2a;
            float qd1 = x0.z, qd2 = x0.w;
            float sT = qd1 * qd2 * sinD;
            float cw = sinD * (qd2 - qd1);
            float rhs1 = (-sT - dVt1) - qd2 * cw;
            float rhs2 = ( sT - dVt2) - qd1 * cw;
            float det = 2.0f - cosD * cosD;
            float inv = __builtin_amdgcn_rcpf(det);
            float qdd1 = (rhs1 - cosD * rhs2) * inv;
            float qdd2 = (2.0f * rhs2 - cosD * rhs1) * inv;
            *reinterpret_cast<float4*>(&out[4 * (S0 + lane)]) = make_float4(qd1, qd2, qdd1, qdd2);
        }
        if (lane < 16 && S0 + 16 + lane < B) {
            float dV0 = dv1[0], dV1 = dv1[1], dV2 = dv1[2], dV3 = dv1[3];
            float cosD = c1b * c2b + s1b * s2b;
            float sinD = s1b * c2b - c1b * s2b;
            float dVt1 = dV0 * c1b - dV1 * s1b;
            float dVt2 = dV2 * c2b - dV3 * s2b;
            float qd1 = x1.z, qd2 = x1.w;
            float sT = qd1 * qd2 * sinD;
            float cw = sinD * (qd2 - qd1);
            float rhs1 = (-sT - dVt1) - qd2 * cw;
            float rhs2 = ( sT - dVt2) - qd1 * cw;
            float det = 2.0f - cosD * cosD;
            float inv = __builtin_amdgcn_rcpf(det);
            float qdd1 = (rhs1 - cosD * rhs2) * inv;
            float qdd2 = (2.0f * rhs2 - cosD * rhs1) * inv;
            *reinterpret_cast<float4*>(&out[4 * (S0 + 16 + lane)]) = make_float4(qd1, qd2, qdd1, qdd2);
        }
    }
}

extern "C" void kernel_launch(void* const* d_in, const int* in_sizes, int n_in,
                              void* d_out, int out_size, void* d_ws, size_t ws_size,
                              hipStream_t stream) {
    const float* X  = (const float*)d_in[0];
    const float* W1 = (const float*)d_in[1];
    const float* b1 = (const float*)d_in[2];
    const float* W2 = (const float*)d_in[3];
    const float* b2 = (const float*)d_in[4];
    const float* W3 = (const float*)d_in[5];
    // d_in[6] = b3: constant offset on V, vanishes in all gradients
    float* out = (float*)d_out;
    int B = in_sizes[0] / 4;
    int duals = (B + 31) >> 5;
    int nchunk = (duals + GRIDB * NW - 1) / (GRIDB * NW);   // == 1 for B=131072
    lnn_kernel<<<GRIDB, TPB, 0, stream>>>(X, W1, b1, b2, W3, W2, out, B, nchunk);
}